// Round 12
// baseline (233.304 us; speedup 1.0000x reference)
//
#include <hip/hip_runtime.h>
#include <hip/hip_bf16.h>

// ---------------- common ----------------
typedef __attribute__((ext_vector_type(4))) int i32x4;
typedef __attribute__((ext_vector_type(16))) int i32x16;

#define M_DIM 8192
#define N_DIM 4096
#define K_DIM 4096
#define BM 256
#define BN 256
#define BK 128
#define NT2 (K_DIM / BK)  // 32

static __device__ inline void gload_lds16(const void* g, void* l) {
  __builtin_amdgcn_global_load_lds(
      (const __attribute__((address_space(1))) unsigned int*)g,
      (__attribute__((address_space(3))) unsigned int*)l,
      16, 0, 0);
}

// ---------------- prep: x fp32 -> i8 (per-row symmetric), row scale + int row-sum ----------------
__global__ __launch_bounds__(256) void prep_x_i8(
    const float* __restrict__ x, char* __restrict__ xq,
    float* __restrict__ rx, float* __restrict__ sxf) {
  const int row = blockIdx.x;
  const int tid = threadIdx.x;
  const float4* xr = (const float4*)(x + (long)row * K_DIM);
  float4 v[4];
  float mx = 0.f;
#pragma unroll
  for (int i = 0; i < 4; ++i) {
    v[i] = xr[i * 256 + tid];
    mx = fmaxf(mx, fmaxf(fmaxf(fabsf(v[i].x), fabsf(v[i].y)),
                         fmaxf(fabsf(v[i].z), fabsf(v[i].w))));
  }
#pragma unroll
  for (int off = 32; off > 0; off >>= 1) mx = fmaxf(mx, __shfl_down(mx, off, 64));
  __shared__ float redm[4];
  __shared__ int reds[4];
  const int lane = tid & 63, w = tid >> 6;
  if (lane == 0) redm[w] = mx;
  __syncthreads();
  const float maxv = fmaxf(fmaxf(redm[0], redm[1]), fmaxf(redm[2], redm[3]));
  const float inv = maxv > 0.f ? 127.f / maxv : 0.f;
  int* xo = (int*)(xq + (long)row * K_DIM);
  int ssum = 0;
#pragma unroll
  for (int i = 0; i < 4; ++i) {
    const int q0 = __float2int_rn(v[i].x * inv);
    const int q1 = __float2int_rn(v[i].y * inv);
    const int q2 = __float2int_rn(v[i].z * inv);
    const int q3 = __float2int_rn(v[i].w * inv);
    ssum += q0 + q1 + q2 + q3;
    xo[i * 256 + tid] =
        (q0 & 255) | ((q1 & 255) << 8) | ((q2 & 255) << 16) | ((q3 & 255) << 24);
  }
#pragma unroll
  for (int off = 32; off > 0; off >>= 1) ssum += __shfl_down(ssum, off, 64);
  if (lane == 0) reds[w] = ssum;
  __syncthreads();
  if (tid == 0) {
    rx[row] = maxv * (1.f / 127.f);
    sxf[row] = (float)(reds[0] + reds[1] + reds[2] + reds[3]);
  }
}

// ---------------- prep: qweight int32 [0,255] -> i8 (q-128), exact ----------------
__global__ __launch_bounds__(256) void prep_q_i8(
    const int* __restrict__ q, char* __restrict__ qb) {
  const long idx = (long)blockIdx.x * blockDim.x + threadIdx.x;  // one int4 -> one int
  const int4 v = ((const int4*)q)[idx];
  const int a = v.x - 128, b = v.y - 128, c = v.z - 128, d = v.w - 128;
  ((int*)qb)[idx] = (a & 255) | ((b & 255) << 8) | ((c & 255) << 16) | ((d & 255) << 24);
}

// ---------------- GEMM: 256x256, BK=128, i8 32x32x32 MFMA ----------------
// A-only LDS staging (32 KB/tile, half of R9's 64 KB — testing the ~12 B/cyc/CU
// global_load_lds throughput cap as the binding constraint). B goes DIRECT to
// registers: per lane a 16B contiguous global load IS the MFMA B-operand
// (row = bcol+wc*64+fn*32+row5, bytes [t*128 + kg*16 + ks*32 .. +16]). B tile
// (32 KB) is L1-resident with 2x wave reuse; B regs double-buffered (sets u/w)
// one tile ahead; compiler auto-vmcnt covers B-reg consumers.
// Ledger: per tile issue [4 A-stages(t+1)][8 B-loads(t+1)]. Completion is
// issue-ordered (m135): at tile end in-flight = 12 -> VMC(8) forces the 4
// A-stages; the 8 B(t+1) stay in flight (consumed next tile via auto-wait).
__global__ __launch_bounds__(512, 2) void wq_gemm_i8(
    const char* __restrict__ A,             // xq [M][K] i8
    const char* __restrict__ B,             // qb [N][K] i8
    const float* __restrict__ rx,           // [M] row scale
    const float* __restrict__ sxf,          // [M] sum of xi (float, exact)
    const float* __restrict__ scales,       // [N]
    const float* __restrict__ zps,          // [N]
    const float* __restrict__ bias,         // [N]
    float* __restrict__ C) {                // [M][N]
  __shared__ __align__(16) char lds[2 * 32768];  // A only: [buf][256 rows x 128B]

  const int tid = threadIdx.x;
  const int lane = tid & 63;
  const int wv = tid >> 6;
  const int wr = wv >> 2, wc = wv & 3;

  // T1: XCD-aware chunked swizzle (nwg=512, 512%8==0).
  const int wg = blockIdx.x;
  const int lid = (wg & 7) * 64 + (wg >> 3);
  const int bx = lid & 15, by = lid >> 4;
  const int brow = by * BM;
  const int bcol = bx * BN;

  i32x16 acc[4][2] = {};

  // ---- A staging: sweep = 512 thr x 16B = 8KB = 64 rows x 128B; 4 sweeps ----
  const int srow = tid >> 3;                           // 0..63 within sweep
  const int schunk = ((tid & 7) ^ (srow & 7)) * 16;    // pre-swizzled source chunk
  const int wub = (tid & ~63) * 16;                    // wave-uniform LDS base
  const char* gAs = A + (long)(brow + srow) * K_DIM + schunk;

#define STAGE_A4(T)                                                           \
  do {                                                                        \
    char* d = lds + ((T) & 1) * 32768;                                        \
    gload_lds16(gAs + (long)(T) * 128, d + wub);                              \
    gload_lds16(gAs + 262144 + (long)(T) * 128, d + 8192 + wub);              \
    gload_lds16(gAs + 524288 + (long)(T) * 128, d + 16384 + wub);             \
    gload_lds16(gAs + 786432 + (long)(T) * 128, d + 24576 + wub);             \
  } while (0)

  // ---- A fragment read offsets (XOR-(row&7) chunk swizzle, both-sides) ----
  // 32x32x32 i8 operand: lane holds [row=lane&31][k = kg*16 + 0..15], kg=lane>>5.
  const int row5 = lane & 31;
  const int kg = lane >> 5;
  int aoff[4];
#pragma unroll
  for (int ks = 0; ks < 4; ++ks) {
    const int ch = ((ks * 2 + kg) ^ (row5 & 7)) * 16;
    aoff[ks] = (wr * 128 + row5) * 128 + ch;
  }

#define RD_A(BB, FM, KS) (*(const i32x4*)(lds + (BB) + aoff[KS] + (FM) * 4096))
#define MMA(FM, FN, AV, BV)                                                   \
  acc[FM][FN] = __builtin_amdgcn_mfma_i32_32x32x32_i8(AV, BV, acc[FM][FN], 0, 0, 0)

#define BAR() __builtin_amdgcn_s_barrier()
#define VMC(N)                                                                \
  do {                                                                        \
    asm volatile("s_waitcnt vmcnt(" #N ")");                                  \
    __builtin_amdgcn_sched_barrier(0);                                        \
  } while (0)
#define SCHED() __builtin_amdgcn_sched_barrier(0)

  // ---- B direct-load base: lane's 16B chunk start for (fn=0, ks=0) ----
  const char* Bp = B + (long)(bcol + wc * 64 + row5) * K_DIM + kg * 16;
  // offsets: + t*128 + fn*131072 (32 rows) + ks*32

  i32x4 u00, u01, u02, u03, u10, u11, u12, u13;  // B set U (fn, ks)
  i32x4 w00, w01, w02, w03, w10, w11, w12, w13;  // B set W

#define LDB(S, T)                                                             \
  do {                                                                        \
    const char* bp = Bp + (long)(T) * 128;                                    \
    S##00 = *(const i32x4*)(bp);                                              \
    S##01 = *(const i32x4*)(bp + 32);                                         \
    S##02 = *(const i32x4*)(bp + 64);                                         \
    S##03 = *(const i32x4*)(bp + 96);                                         \
    S##10 = *(const i32x4*)(bp + 131072);                                     \
    S##11 = *(const i32x4*)(bp + 131072 + 32);                                \
    S##12 = *(const i32x4*)(bp + 131072 + 64);                                \
    S##13 = *(const i32x4*)(bp + 131072 + 96);                                \
  } while (0)

#define COMPUTE(BB, S)                                                        \
  do {                                                                        \
    i32x4 a0, a1, a2, a3;                                                     \
    a0 = RD_A(BB, 0, 0); a1 = RD_A(BB, 0, 1); a2 = RD_A(BB, 0, 2); a3 = RD_A(BB, 0, 3); \
    MMA(0, 0, a0, S##00); MMA(0, 1, a0, S##10);                               \
    MMA(0, 0, a1, S##01); MMA(0, 1, a1, S##11);                               \
    MMA(0, 0, a2, S##02); MMA(0, 1, a2, S##12);                               \
    MMA(0, 0, a3, S##03); MMA(0, 1, a3, S##13);                               \
    a0 = RD_A(BB, 1, 0); a1 = RD_A(BB, 1, 1); a2 = RD_A(BB, 1, 2); a3 = RD_A(BB, 1, 3); \
    MMA(1, 0, a0, S##00); MMA(1, 1, a0, S##10);                               \
    MMA(1, 0, a1, S##01); MMA(1, 1, a1, S##11);                               \
    MMA(1, 0, a2, S##02); MMA(1, 1, a2, S##12);                               \
    MMA(1, 0, a3, S##03); MMA(1, 1, a3, S##13);                               \
    a0 = RD_A(BB, 2, 0); a1 = RD_A(BB, 2, 1); a2 = RD_A(BB, 2, 2); a3 = RD_A(BB, 2, 3); \
    MMA(2, 0, a0, S##00); MMA(2, 1, a0, S##10);                               \
    MMA(2, 0, a1, S##01); MMA(2, 1, a1, S##11);                               \
    MMA(2, 0, a2, S##02); MMA(2, 1, a2, S##12);                               \
    MMA(2, 0, a3, S##03); MMA(2, 1, a3, S##13);                               \
    a0 = RD_A(BB, 3, 0); a1 = RD_A(BB, 3, 1); a2 = RD_A(BB, 3, 2); a3 = RD_A(BB, 3, 3); \
    MMA(3, 0, a0, S##00); MMA(3, 1, a0, S##10);                               \
    MMA(3, 0, a1, S##01); MMA(3, 1, a1, S##11);                               \
    MMA(3, 0, a2, S##02); MMA(3, 1, a2, S##12);                               \
    MMA(3, 0, a3, S##03); MMA(3, 1, a3, S##13);                               \
  } while (0)

// Tile body: stage A(t+1), load B(t+1)->NXT, compute tile t with A-LDS + CUR,
// then VMC(8) forces the 4 A-stages (8 B-loads stay in flight), barrier.
#define TILE_BODY(T, CUR, NXT)                                                \
  do {                                                                        \
    const int bb_ = ((T) & 1) * 32768;                                        \
    STAGE_A4((T) + 1);                                                        \
    SCHED();                                                                  \
    LDB(NXT, (T) + 1);                                                        \
    SCHED();                                                                  \
    COMPUTE(bb_, CUR);                                                        \
    VMC(8);                                                                   \
    BAR();                                                                    \
  } while (0)

  // ---- prologue: stage A(0), load B(0)->U ----
  STAGE_A4(0);
  SCHED();
  LDB(u, 0);
  SCHED();
  VMC(8);  // in-flight 12 -> forces the 4 A-stages; B(0) flies (auto-wait at use)
  BAR();

  // ---- main loop: tiles 0..29 in parity pairs ----
  for (int tp = 0; tp < 15; ++tp) {
    TILE_BODY(2 * tp, u, w);
    TILE_BODY(2 * tp + 1, w, u);
  }
  // ---- tile 30 (consume U, stage/load 31 -> W) ----
  TILE_BODY(30, u, w);
  // ---- tile 31 (consume W, no staging) ----
  COMPUTE(32768, w);

  // ---- epilogue: C/D layout col=lane&31, row=(r&3)+8*(r>>2)+4*kg (dtype-indep) ----
  // y = s * rx * (dot_i32 + (128 - zp) * sum_xi) + b
  float sc[2], zp[2], bs[2];
  int coln[2];
#pragma unroll
  for (int fn = 0; fn < 2; ++fn) {
    coln[fn] = bcol + wc * 64 + fn * 32 + row5;
    sc[fn] = scales[coln[fn]];
    zp[fn] = 128.f - zps[coln[fn]];
    bs[fn] = bias[coln[fn]];
  }
#pragma unroll
  for (int fm = 0; fm < 4; ++fm) {
#pragma unroll
    for (int r = 0; r < 16; ++r) {
      const int grow = brow + wr * 128 + fm * 32 + (r & 3) + 8 * (r >> 2) + 4 * kg;
      const float rxv = rx[grow];
      const float sxv = sxf[grow];
#pragma unroll
      for (int fn = 0; fn < 2; ++fn) {
        C[(long)grow * N_DIM + coln[fn]] =
            sc[fn] * rxv * ((float)acc[fm][fn][r] + zp[fn] * sxv) + bs[fn];
      }
    }
  }
}

// ---------------- launch ----------------
extern "C" void kernel_launch(void* const* d_in, const int* in_sizes, int n_in,
                              void* d_out, int out_size, void* d_ws, size_t ws_size,
                              hipStream_t stream) {
  const float* x = (const float*)d_in[0];
  const int* qw = (const int*)d_in[1];
  const float* scales = (const float*)d_in[2];
  const float* zps = (const float*)d_in[3];
  const float* bias = (const float*)d_in[4];
  float* out = (float*)d_out;

  char* ws = (char*)d_ws;
  char* xq = ws;                                             // 32 MB i8
  char* qb = ws + (size_t)32 * 1024 * 1024;                  // 16 MB i8
  float* rx = (float*)(ws + (size_t)48 * 1024 * 1024);       // 32 KB
  float* sxf = (float*)(ws + (size_t)48 * 1024 * 1024 + 65536);  // 32 KB

  hipLaunchKernelGGL(prep_x_i8, dim3(M_DIM), dim3(256), 0, stream, x, xq, rx, sxf);
  hipLaunchKernelGGL(prep_q_i8, dim3((N_DIM * K_DIM / 4) / 256), dim3(256), 0, stream,
                     qw, qb);
  hipLaunchKernelGGL(wq_gemm_i8, dim3((M_DIM / BM) * (N_DIM / BN)), dim3(512), 0,
                     stream, xq, qb, rx, sxf, scales, zps, bias, out);
}

// Round 13
// 221.594 us; speedup vs baseline: 1.0528x; 1.0528x over previous
//
#include <hip/hip_runtime.h>
#include <hip/hip_bf16.h>

// ---------------- common ----------------
typedef __attribute__((ext_vector_type(4))) int i32x4;
typedef __attribute__((ext_vector_type(16))) int i32x16;

#define M_DIM 8192
#define N_DIM 4096
#define K_DIM 4096
#define BM 128
#define BN 128
#define BK 128
#define NT2 (K_DIM / BK)  // 32

static __device__ inline void gload_lds16(const void* g, void* l) {
  __builtin_amdgcn_global_load_lds(
      (const __attribute__((address_space(1))) unsigned int*)g,
      (__attribute__((address_space(3))) unsigned int*)l,
      16, 0, 0);
}

// ---------------- prep: x fp32 -> i8 (per-row symmetric), row scale + int row-sum ----------------
__global__ __launch_bounds__(256) void prep_x_i8(
    const float* __restrict__ x, char* __restrict__ xq,
    float* __restrict__ rx, float* __restrict__ sxf) {
  const int row = blockIdx.x;
  const int tid = threadIdx.x;
  const float4* xr = (const float4*)(x + (long)row * K_DIM);
  float4 v[4];
  float mx = 0.f;
#pragma unroll
  for (int i = 0; i < 4; ++i) {
    v[i] = xr[i * 256 + tid];
    mx = fmaxf(mx, fmaxf(fmaxf(fabsf(v[i].x), fabsf(v[i].y)),
                         fmaxf(fabsf(v[i].z), fabsf(v[i].w))));
  }
#pragma unroll
  for (int off = 32; off > 0; off >>= 1) mx = fmaxf(mx, __shfl_down(mx, off, 64));
  __shared__ float redm[4];
  __shared__ int reds[4];
  const int lane = tid & 63, w = tid >> 6;
  if (lane == 0) redm[w] = mx;
  __syncthreads();
  const float maxv = fmaxf(fmaxf(redm[0], redm[1]), fmaxf(redm[2], redm[3]));
  const float inv = maxv > 0.f ? 127.f / maxv : 0.f;
  int* xo = (int*)(xq + (long)row * K_DIM);
  int ssum = 0;
#pragma unroll
  for (int i = 0; i < 4; ++i) {
    const int q0 = __float2int_rn(v[i].x * inv);
    const int q1 = __float2int_rn(v[i].y * inv);
    const int q2 = __float2int_rn(v[i].z * inv);
    const int q3 = __float2int_rn(v[i].w * inv);
    ssum += q0 + q1 + q2 + q3;
    xo[i * 256 + tid] =
        (q0 & 255) | ((q1 & 255) << 8) | ((q2 & 255) << 16) | ((q3 & 255) << 24);
  }
#pragma unroll
  for (int off = 32; off > 0; off >>= 1) ssum += __shfl_down(ssum, off, 64);
  if (lane == 0) reds[w] = ssum;
  __syncthreads();
  if (tid == 0) {
    rx[row] = maxv * (1.f / 127.f);
    sxf[row] = (float)(reds[0] + reds[1] + reds[2] + reds[3]);
  }
}

// ---------------- prep: qweight int32 [0,255] -> i8 (q-128), exact ----------------
__global__ __launch_bounds__(256) void prep_q_i8(
    const int* __restrict__ q, char* __restrict__ qb) {
  const long idx = (long)blockIdx.x * blockDim.x + threadIdx.x;  // one int4 -> one int
  const int4 v = ((const int4*)q)[idx];
  const int a = v.x - 128, b = v.y - 128, c = v.z - 128, d = v.w - 128;
  ((int*)qb)[idx] = (a & 255) | ((b & 255) << 8) | ((c & 255) << 16) | ((d & 255) << 24);
}

// ---------------- GEMM: 128x128 tiles, 4 waves, 2 blocks/CU, i8 32x32x32 MFMA ----------------
// Block-level phase decorrelation: 2 independent blocks per CU (LDS 64KB each) share
// no barriers, so one block's read/stage phases overlap the other block's MFMA
// regions — the per-CU LDS pipe and the SIMD matrix pipes run concurrently even
// though each block is internally lockstep (m97/m114 mechanism; 1-block 256² tiles
// structurally forbade this, explaining four rounds of serial LDS+MFMA timing).
// Geometry: conflict-free 128B rows, XOR-(row&7) chunk swizzle both-sides.
// Per K-tile per block: 8 gload_lds (A 16KB + B 16KB), per wave 16 ds_read_b128 +
// 16 MFMA (wave tile 64x64 = 2fm x 2fn).
// Ledger: iter t: STAGE(t+1) {8} -> in-flight 16 -> VMC(8) forces tile t's 8 ->
// BAR -> COMPUTE(t) -> BAR (all reads of buf done before next iter's STAGE).
__global__ __launch_bounds__(256, 2) void wq_gemm_i8(
    const char* __restrict__ A,             // xq [M][K] i8
    const char* __restrict__ B,             // qb [N][K] i8
    const float* __restrict__ rx,           // [M] row scale
    const float* __restrict__ sxf,          // [M] sum of xi (float, exact)
    const float* __restrict__ scales,       // [N]
    const float* __restrict__ zps,          // [N]
    const float* __restrict__ bias,         // [N]
    float* __restrict__ C) {                // [M][N]
  __shared__ __align__(16) char lds[2 * 32768];  // [buf][A:16KB | B:16KB]

  const int tid = threadIdx.x;
  const int lane = tid & 63;
  const int wv = tid >> 6;
  const int wr = wv >> 1, wc = wv & 1;  // 2x2 waves; wave tile 64x64

  // T1: XCD-aware chunked swizzle (nwg=2048, 2048%8==0 -> bijective).
  // XCD x gets lids x*256..x*256+255: 8 consecutive A-panels x all 32 B-panels.
  const int wg = blockIdx.x;
  const int lid = (wg & 7) * 256 + (wg >> 3);
  const int bx = lid & 31, by = lid >> 5;
  const int brow = by * BM;
  const int bcol = bx * BN;

  i32x16 acc[2][2] = {};

  // ---- staging: sweep = 256 thr x 16B = 4KB = 32 rows x 128B; 4 sweeps/matrix ----
  const int srow = tid >> 3;                           // 0..31 within sweep
  const int schunk = ((tid & 7) ^ (srow & 7)) * 16;    // pre-swizzled source chunk
  const int wub = (tid & ~63) * 16;                    // wave-uniform LDS base
  const char* gAs = A + (long)(brow + srow) * K_DIM + schunk;
  const char* gBs = B + (long)(bcol + srow) * K_DIM + schunk;

#define STAGE(T)                                                              \
  do {                                                                        \
    char* d = lds + ((T) & 1) * 32768;                                        \
    gload_lds16(gAs + (long)(T) * 128, d + wub);                              \
    gload_lds16(gAs + 131072 + (long)(T) * 128, d + 4096 + wub);              \
    gload_lds16(gAs + 262144 + (long)(T) * 128, d + 8192 + wub);              \
    gload_lds16(gAs + 393216 + (long)(T) * 128, d + 12288 + wub);             \
    gload_lds16(gBs + (long)(T) * 128, d + 16384 + wub);                      \
    gload_lds16(gBs + 131072 + (long)(T) * 128, d + 20480 + wub);             \
    gload_lds16(gBs + 262144 + (long)(T) * 128, d + 24576 + wub);             \
    gload_lds16(gBs + 393216 + (long)(T) * 128, d + 28672 + wub);             \
  } while (0)

  // ---- fragment read offsets ----
  // 32x32x32 i8 operand: lane holds [row=lane&31][k = kg*16 + 0..15], kg=lane>>5.
  // Within a 128B row: chunk(ks) = ks*2 + kg, swizzled by XOR (row&7).
  const int row5 = lane & 31;
  const int kg = lane >> 5;
  int aoff[4], boff[4];
#pragma unroll
  for (int ks = 0; ks < 4; ++ks) {
    const int ch = ((ks * 2 + kg) ^ (row5 & 7)) * 16;
    aoff[ks] = (wr * 64 + row5) * 128 + ch;           // + fm*4096 (32 rows)
    boff[ks] = 16384 + (wc * 64 + row5) * 128 + ch;   // + fn*4096
  }

#define RD_A(BB, FM, KS) (*(const i32x4*)(lds + (BB) + aoff[KS] + (FM) * 4096))
#define RD_B(BB, FN, KS) (*(const i32x4*)(lds + (BB) + boff[KS] + (FN) * 4096))
#define MMA(FM, FN, AV, BV)                                                   \
  acc[FM][FN] = __builtin_amdgcn_mfma_i32_32x32x32_i8(AV, BV, acc[FM][FN], 0, 0, 0)

#define BAR() __builtin_amdgcn_s_barrier()
#define VMC(N)                                                                \
  do {                                                                        \
    asm volatile("s_waitcnt vmcnt(" #N ")");                                  \
    __builtin_amdgcn_sched_barrier(0);                                        \
  } while (0)

#define COMPUTE(BB)                                                           \
  do {                                                                        \
    i32x4 a00 = RD_A(BB, 0, 0), a01 = RD_A(BB, 0, 1);                         \
    i32x4 a02 = RD_A(BB, 0, 2), a03 = RD_A(BB, 0, 3);                         \
    i32x4 a10 = RD_A(BB, 1, 0), a11 = RD_A(BB, 1, 1);                         \
    i32x4 a12 = RD_A(BB, 1, 2), a13 = RD_A(BB, 1, 3);                         \
    i32x4 b00 = RD_B(BB, 0, 0), b01 = RD_B(BB, 0, 1);                         \
    i32x4 b02 = RD_B(BB, 0, 2), b03 = RD_B(BB, 0, 3);                         \
    i32x4 b10 = RD_B(BB, 1, 0), b11 = RD_B(BB, 1, 1);                         \
    i32x4 b12 = RD_B(BB, 1, 2), b13 = RD_B(BB, 1, 3);                         \
    MMA(0, 0, a00, b00); MMA(0, 1, a00, b10);                                 \
    MMA(1, 0, a10, b00); MMA(1, 1, a10, b10);                                 \
    MMA(0, 0, a01, b01); MMA(0, 1, a01, b11);                                 \
    MMA(1, 0, a11, b01); MMA(1, 1, a11, b11);                                 \
    MMA(0, 0, a02, b02); MMA(0, 1, a02, b12);                                 \
    MMA(1, 0, a12, b02); MMA(1, 1, a12, b12);                                 \
    MMA(0, 0, a03, b03); MMA(0, 1, a03, b13);                                 \
    MMA(1, 0, a13, b03); MMA(1, 1, a13, b13);                                 \
  } while (0)

  // ---- prologue ----
  STAGE(0);
  VMC(0);
  BAR();

  // ---- main loop: tiles 0..NT2-2 ----
  for (int t = 0; t < NT2 - 1; ++t) {
    const int bb = (t & 1) * 32768;
    STAGE(t + 1);   // in-flight 16
    VMC(8);         // forces tile t's 8 (t+1's 8 stay in flight)
    BAR();
    COMPUTE(bb);
    BAR();          // all reads of buf done before next iter's STAGE overwrites
  }

  // ---- tail: tile NT2-1 ----
  {
    VMC(0);
    BAR();
    COMPUTE(((NT2 - 1) & 1) * 32768);
  }

  // ---- epilogue: C/D layout col=lane&31, row=(r&3)+8*(r>>2)+4*kg (dtype-indep) ----
  // y = s * rx * (dot_i32 + (128 - zp) * sum_xi) + b
  float sc[2], zp[2], bs[2];
  int coln[2];
#pragma unroll
  for (int fn = 0; fn < 2; ++fn) {
    coln[fn] = bcol + wc * 64 + fn * 32 + row5;
    sc[fn] = scales[coln[fn]];
    zp[fn] = 128.f - zps[coln[fn]];
    bs[fn] = bias[coln[fn]];
  }
#pragma unroll
  for (int fm = 0; fm < 2; ++fm) {
#pragma unroll
    for (int r = 0; r < 16; ++r) {
      const int grow = brow + wr * 64 + fm * 32 + (r & 3) + 8 * (r >> 2) + 4 * kg;
      const float rxv = rx[grow];
      const float sxv = sxf[grow];
#pragma unroll
      for (int fn = 0; fn < 2; ++fn) {
        C[(long)grow * N_DIM + coln[fn]] =
            sc[fn] * rxv * ((float)acc[fm][fn][r] + zp[fn] * sxv) + bs[fn];
      }
    }
  }
}

// ---------------- launch ----------------
extern "C" void kernel_launch(void* const* d_in, const int* in_sizes, int n_in,
                              void* d_out, int out_size, void* d_ws, size_t ws_size,
                              hipStream_t stream) {
  const float* x = (const float*)d_in[0];
  const int* qw = (const int*)d_in[1];
  const float* scales = (const float*)d_in[2];
  const float* zps = (const float*)d_in[3];
  const float* bias = (const float*)d_in[4];
  float* out = (float*)d_out;

  char* ws = (char*)d_ws;
  char* xq = ws;                                             // 32 MB i8
  char* qb = ws + (size_t)32 * 1024 * 1024;                  // 16 MB i8
  float* rx = (float*)(ws + (size_t)48 * 1024 * 1024);       // 32 KB
  float* sxf = (float*)(ws + (size_t)48 * 1024 * 1024 + 65536);  // 32 KB

  hipLaunchKernelGGL(prep_x_i8, dim3(M_DIM), dim3(256), 0, stream, x, xq, rx, sxf);
  hipLaunchKernelGGL(prep_q_i8, dim3((N_DIM * K_DIM / 4) / 256), dim3(256), 0, stream,
                     qw, qb);
  hipLaunchKernelGGL(wq_gemm_i8, dim3((M_DIM / BM) * (N_DIM / BN)), dim3(256), 0,
                     stream, xq, qb, rx, sxf, scales, zps, bias, out);
}

// Round 14
// 179.464 us; speedup vs baseline: 1.3000x; 1.2348x over previous
//
#include <hip/hip_runtime.h>
#include <hip/hip_bf16.h>

// ---------------- common ----------------
typedef __attribute__((ext_vector_type(4))) int i32x4;

#define M_DIM 8192
#define N_DIM 4096
#define K_DIM 4096
#define BM 256
#define BN 256
#define BK 128
#define NT2 (K_DIM / BK)  // 32

static __device__ inline void gload_lds16(const void* g, void* l) {
  __builtin_amdgcn_global_load_lds(
      (const __attribute__((address_space(1))) unsigned int*)g,
      (__attribute__((address_space(3))) unsigned int*)l,
      16, 0, 0);
}

// ---------------- prep: x fp32 -> i8 (per-row symmetric), row scale + int row-sum ----------------
__global__ __launch_bounds__(256) void prep_x_i8(
    const float* __restrict__ x, char* __restrict__ xq,
    float* __restrict__ rx, float* __restrict__ sxf) {
  const int row = blockIdx.x;
  const int tid = threadIdx.x;
  const float4* xr = (const float4*)(x + (long)row * K_DIM);
  float4 v[4];
  float mx = 0.f;
#pragma unroll
  for (int i = 0; i < 4; ++i) {
    v[i] = xr[i * 256 + tid];
    mx = fmaxf(mx, fmaxf(fmaxf(fabsf(v[i].x), fabsf(v[i].y)),
                         fmaxf(fabsf(v[i].z), fabsf(v[i].w))));
  }
#pragma unroll
  for (int off = 32; off > 0; off >>= 1) mx = fmaxf(mx, __shfl_down(mx, off, 64));
  __shared__ float redm[4];
  __shared__ int reds[4];
  const int lane = tid & 63, w = tid >> 6;
  if (lane == 0) redm[w] = mx;
  __syncthreads();
  const float maxv = fmaxf(fmaxf(redm[0], redm[1]), fmaxf(redm[2], redm[3]));
  const float inv = maxv > 0.f ? 127.f / maxv : 0.f;
  int* xo = (int*)(xq + (long)row * K_DIM);
  int ssum = 0;
#pragma unroll
  for (int i = 0; i < 4; ++i) {
    const int q0 = __float2int_rn(v[i].x * inv);
    const int q1 = __float2int_rn(v[i].y * inv);
    const int q2 = __float2int_rn(v[i].z * inv);
    const int q3 = __float2int_rn(v[i].w * inv);
    ssum += q0 + q1 + q2 + q3;
    xo[i * 256 + tid] =
        (q0 & 255) | ((q1 & 255) << 8) | ((q2 & 255) << 16) | ((q3 & 255) << 24);
  }
#pragma unroll
  for (int off = 32; off > 0; off >>= 1) ssum += __shfl_down(ssum, off, 64);
  if (lane == 0) reds[w] = ssum;
  __syncthreads();
  if (tid == 0) {
    rx[row] = maxv * (1.f / 127.f);
    sxf[row] = (float)(reds[0] + reds[1] + reds[2] + reds[3]);
  }
}

// ---------------- prep: qweight int32 [0,255] -> i8 (q-128), exact ----------------
__global__ __launch_bounds__(256) void prep_q_i8(
    const int* __restrict__ q, char* __restrict__ qb) {
  const long idx = (long)blockIdx.x * blockDim.x + threadIdx.x;  // one int4 -> one int
  const int4 v = ((const int4*)q)[idx];
  const int a = v.x - 128, b = v.y - 128, c = v.z - 128, d = v.w - 128;
  ((int*)qb)[idx] = (a & 255) | ((b & 255) << 8) | ((c & 255) << 16) | ((d & 255) << 24);
}

// ---------------- GEMM: 256x256, BK=128, i8 *16x16x64* MFMA (shape A/B vs R9) ----------------
// Identical to the 146-µs R9 kernel except the MFMA shape: 16x16x64 (20.4 cyc issue)
// replaces 32x32x32 (36.6 cyc). Mechanism under test: short MFMAs leave SIMD issue
// gaps that let co-waves' ds_read/staging interleave into the matrix-pipe shadow
// (m201/m97 families — the only kernels in the corpus that overlap LDS with MFMA —
// are 16x16; every 32x32 kernel of ours timed as LDS+MFMA summed).
// Geometry: conflict-free 128B rows, XOR-(row&7) chunk swizzle both-sides.
// Wave tile 128x64 = 8 fm x 4 fn 16x16 frags; 64 MFMA + 24 ds_read_b128 per tile.
// Ledger (= R9): per tile t: half1 stages G1(t+1) = {A0,A2,B0,B2,B1,B3} (6 loads),
// half2 stages G2(t+1) = {A1,A3} (2).
//   mid-tile:  in-flight = G2(t){2} + G1(t+1){6} -> VMC(6) forces G2(t)
//              (half2 reads A sweeps {2wr+1} in {1,3})
//   boundary:  in-flight = G1(t+1){6} + G2(t+1){2} -> VMC(2) forces G1(t+1)
//              (next half1 reads A sweeps {2wr} in {0,2} + all B)
__global__ __launch_bounds__(512, 2) void wq_gemm_i8(
    const char* __restrict__ A,             // xq [M][K] i8
    const char* __restrict__ B,             // qb [N][K] i8
    const float* __restrict__ rx,           // [M] row scale
    const float* __restrict__ sxf,          // [M] sum of xi (float, exact)
    const float* __restrict__ scales,       // [N]
    const float* __restrict__ zps,          // [N]
    const float* __restrict__ bias,         // [N]
    float* __restrict__ C) {                // [M][N]
  __shared__ __align__(16) char lds[2 * 65536];  // [buf][A:32KB | B:32KB]

  const int tid = threadIdx.x;
  const int lane = tid & 63;
  const int wv = tid >> 6;
  const int wr = wv >> 2, wc = wv & 3;

  // T1: XCD-aware chunked swizzle (nwg=512, 512%8==0).
  const int wg = blockIdx.x;
  const int lid = (wg & 7) * 64 + (wg >> 3);
  const int bx = lid & 15, by = lid >> 4;
  const int brow = by * BM;
  const int bcol = bx * BN;

  i32x4 acc[8][4] = {};  // 8 fm x 4 fn x 4 i32 = 128 AGPR

  // ---- staging: sweep = 512 thr x 16B = 8KB = 64 rows x 128B; 4 sweeps per matrix ----
  const int srow = tid >> 3;                           // 0..63 within sweep
  const int schunk = ((tid & 7) ^ (srow & 7)) * 16;    // pre-swizzled source chunk
  const int wub = (tid & ~63) * 16;                    // wave-uniform LDS base
  const char* gAs = A + (long)(brow + srow) * K_DIM + schunk;
  const char* gBs = B + (long)(bcol + srow) * K_DIM + schunk;

#define STAGE_A2(T, J0, J1)                                                   \
  do {                                                                        \
    char* d = lds + ((T) & 1) * 65536;                                        \
    gload_lds16(gAs + (long)(J0) * 262144 + (long)(T) * 128,                  \
                d + (J0) * 8192 + wub);                                       \
    gload_lds16(gAs + (long)(J1) * 262144 + (long)(T) * 128,                  \
                d + (J1) * 8192 + wub);                                       \
  } while (0)
#define STAGE_B2(T, J0, J1)                                                   \
  do {                                                                        \
    char* d = lds + ((T) & 1) * 65536 + 32768;                                \
    gload_lds16(gBs + (long)(J0) * 262144 + (long)(T) * 128,                  \
                d + (J0) * 8192 + wub);                                       \
    gload_lds16(gBs + (long)(J1) * 262144 + (long)(T) * 128,                  \
                d + (J1) * 8192 + wub);                                       \
  } while (0)

  // ---- fragment read offsets ----
  // 16x16x64 i8 operand: lane holds [row=lane&15][k = (lane>>4)*16 + 0..15].
  // Byte offset within 128B row = ks*64 + kq*16 -> chunk = ks*4+kq, XOR (row&7)
  // (fm*16 and wr*128 are ≡0 mod 8, so the XOR term is lane-constant).
  const int row15 = lane & 15;
  const int kq = lane >> 4;  // 0..3
  int aoff[2], boff[2];
#pragma unroll
  for (int ks = 0; ks < 2; ++ks) {
    const int ch = ((ks * 4 + kq) ^ (row15 & 7)) * 16;
    aoff[ks] = (wr * 128 + row15) * 128 + ch;           // + fm*2048 (16 rows)
    boff[ks] = 32768 + (wc * 64 + row15) * 128 + ch;    // + fn*2048
  }

#define RD_A(BB, FM, KS) (*(const i32x4*)(lds + (BB) + aoff[KS] + (FM) * 2048))
#define RD_B(BB, FN, KS) (*(const i32x4*)(lds + (BB) + boff[KS] + (FN) * 2048))
#define MMA(FM, FN, AV, BV)                                                   \
  acc[FM][FN] = __builtin_amdgcn_mfma_i32_16x16x64_i8(AV, BV, acc[FM][FN], 0, 0, 0)

#define BAR() __builtin_amdgcn_s_barrier()
#define VMC(N)                                                                \
  do {                                                                        \
    asm volatile("s_waitcnt vmcnt(" #N ")");                                  \
    __builtin_amdgcn_sched_barrier(0);                                        \
  } while (0)

  // half: FM0 = base fm (0 or 4). Reads 8 A-frags + (half1 only) 8 B-frags; 32 MFMA.
#define HALF_MMA(BB, FM0, AF, BF)                                             \
  do {                                                                        \
    _Pragma("unroll") for (int f = 0; f < 4; ++f)                             \
      _Pragma("unroll") for (int ks = 0; ks < 2; ++ks)                        \
        AF[f][ks] = RD_A(BB, (FM0) + f, ks);                                  \
    _Pragma("unroll") for (int ks = 0; ks < 2; ++ks)                          \
      _Pragma("unroll") for (int f = 0; f < 4; ++f)                           \
        _Pragma("unroll") for (int n = 0; n < 4; ++n)                         \
          MMA((FM0) + f, n, AF[f][ks], BF[n][ks]);                            \
  } while (0)

  // ---- prologue: stage tile 0 into buf0 (G1 then G2 order) ----
  STAGE_A2(0, 0, 2);
  STAGE_B2(0, 0, 2);
  STAGE_B2(0, 1, 3);
  STAGE_A2(0, 1, 3);
  VMC(2);  // G1(0) landed; G2(0)={A1,A3} may fly until mid-tile VMC
  BAR();

  i32x4 af[4][2], bf[4][2];

  // ---- main loop: tiles 0..NT2-2, staging t+1 into other buf ----
  for (int t = 0; t < NT2 - 1; ++t) {
    const int bb = (t & 1) * 65536;
    const int t1 = t + 1;
    // ---- half1: fm 0..3 (A sweep 2wr in {0,2}) + all B ----
#pragma unroll
    for (int n = 0; n < 4; ++n)
#pragma unroll
      for (int ks = 0; ks < 2; ++ks) bf[n][ks] = RD_B(bb, n, ks);
    STAGE_A2(t1, 0, 2);      // G1(t+1): 6 loads
    STAGE_B2(t1, 0, 2);
    STAGE_B2(t1, 1, 3);
    HALF_MMA(bb, 0, af, bf);
    VMC(6);  // G2(t)={A1,A3} landed -> half2's A-sweep-{1,3} reads safe
    BAR();
    // ---- half2: fm 4..7 (A sweep 2wr+1 in {1,3}) ----
    STAGE_A2(t1, 1, 3);      // G2(t+1): 2 loads
    HALF_MMA(bb, 4, af, bf);
    VMC(2);  // G1(t+1) landed -> next half1 safe (G2(t+1) may fly)
    BAR();
  }

  // ---- tail: tile NT2-1 (odd -> buf1), no staging ----
  {
    const int bb = 65536;
#pragma unroll
    for (int n = 0; n < 4; ++n)
#pragma unroll
      for (int ks = 0; ks < 2; ++ks) bf[n][ks] = RD_B(bb, n, ks);
    HALF_MMA(bb, 0, af, bf);
    VMC(0);  // drain this tile's {A1,A3}
    BAR();
    HALF_MMA(bb, 4, af, bf);
  }

  // ---- epilogue: 16x16 C/D layout col=lane&15, row=kq*4+j (m89-verified) ----
  // y = s * rx * (dot_i32 + (128 - zp) * sum_xi) + b
  float sc[4], zp[4], bs[4];
  int coln[4];
#pragma unroll
  for (int fn = 0; fn < 4; ++fn) {
    coln[fn] = bcol + wc * 64 + fn * 16 + row15;
    sc[fn] = scales[coln[fn]];
    zp[fn] = 128.f - zps[coln[fn]];
    bs[fn] = bias[coln[fn]];
  }
#pragma unroll
  for (int fm = 0; fm < 8; ++fm) {
    const int r0 = brow + wr * 128 + fm * 16 + kq * 4;
#pragma unroll
    for (int j = 0; j < 4; ++j) {
      const int grow = r0 + j;
      const float rxv = rx[grow];
      const float sxv = sxf[grow];
#pragma unroll
      for (int fn = 0; fn < 4; ++fn) {
        C[(long)grow * N_DIM + coln[fn]] =
            sc[fn] * rxv * ((float)acc[fm][fn][j] + zp[fn] * sxv) + bs[fn];
      }
    }
  }
}

// ---------------- launch ----------------
extern "C" void kernel_launch(void* const* d_in, const int* in_sizes, int n_in,
                              void* d_out, int out_size, void* d_ws, size_t ws_size,
                              hipStream_t stream) {
  const float* x = (const float*)d_in[0];
  const int* qw = (const int*)d_in[1];
  const float* scales = (const float*)d_in[2];
  const float* zps = (const float*)d_in[3];
  const float* bias = (const float*)d_in[4];
  float* out = (float*)d_out;

  char* ws = (char*)d_ws;
  char* xq = ws;                                             // 32 MB i8
  char* qb = ws + (size_t)32 * 1024 * 1024;                  // 16 MB i8
  float* rx = (float*)(ws + (size_t)48 * 1024 * 1024);       // 32 KB
  float* sxf = (float*)(ws + (size_t)48 * 1024 * 1024 + 65536);  // 32 KB

  hipLaunchKernelGGL(prep_x_i8, dim3(M_DIM), dim3(256), 0, stream, x, xq, rx, sxf);
  hipLaunchKernelGGL(prep_q_i8, dim3((N_DIM * K_DIM / 4) / 256), dim3(256), 0, stream,
                     qw, qb);
  hipLaunchKernelGGL(wq_gemm_i8, dim3((M_DIM / BM) * (N_DIM / BN)), dim3(512), 0,
                     stream, xq, qb, rx, sxf, scales, zps, bias, out);
}